// Round 8
// baseline (261.630 us; speedup 1.0000x reference)
//
#include <hip/hip_runtime.h>
#include <math.h>

// NonLocalBlock: B=4, C=256, Cb=128, H=W=64, N=HW=4096.
// Round 8: k3 = 128n x 64c blocks (c-split keeps 1024 blocks / 4 per CU while
// halving unique L2 bytes per n-work vs r6); k2 m-tile 128 (halves theta L2).
// r7 lesson: Nt=128 with only 512 blocks starved the CU (occupancy 20%).
constexpr int CI = 256;
constexpr int CB = 128;
constexpr int HWD = 4096;
constexpr int NBATCH = 4;
constexpr int NN_ = 4096;
constexpr size_t U1 = (size_t)NBATCH * NN_ * CB;            // 2,097,152
constexpr size_t U_THETA = 0;
constexpr size_t U_PHIT  = U1;
constexpr size_t U_G     = 2 * U1;
constexpr size_t U_GT    = 3 * U1;
constexpr size_t U_Y     = 4 * U1;                          // 4 m-quarter partials
constexpr size_t U_XT    = 4 * U1;                          // alias (xT dead before k3)
constexpr size_t U_WCAT  = 8 * U1;
constexpr size_t U_WW    = 8 * U1 + 98304;
constexpr size_t F_D     = (8 * U1 + 131072) / 2;

typedef short v8s __attribute__((ext_vector_type(8)));
typedef unsigned short u8s __attribute__((ext_vector_type(8)));
typedef float v4f __attribute__((ext_vector_type(4)));
typedef float v16f __attribute__((ext_vector_type(16)));
#define MFMA16(a, b, c) __builtin_amdgcn_mfma_f32_16x16x32_bf16(a, b, c, 0, 0, 0)
#define MFMA32(a, b, c) __builtin_amdgcn_mfma_f32_32x32x16_bf16(a, b, c, 0, 0, 0)

__device__ __forceinline__ unsigned short f2bf(float f) {
    union { float f; unsigned u; } v; v.f = f;
    unsigned r = v.u + 0x7fff + ((v.u >> 16) & 1);
    return (unsigned short)(r >> 16);
}
__device__ __forceinline__ float bf2f(unsigned short s) {
    union { unsigned u; float f; } v; v.u = (unsigned)s << 16;
    return v.f;
}

// ---------------- k0: xT transpose + (fused) weight bf16 convert ------------
__global__ __launch_bounds__(256) void k0_xpose(
    const float* __restrict__ x, unsigned short* __restrict__ xT,
    const float* __restrict__ tw, const float* __restrict__ pw,
    const float* __restrict__ gw, const float* __restrict__ Ww,
    unsigned short* __restrict__ wcat, unsigned short* __restrict__ wwB)
{
    __shared__ unsigned short T[64 * 72];
    const int t = threadIdx.x;
    if (blockIdx.y == 4) {
        int wb = blockIdx.x + 64 * blockIdx.z;
        if (t < 128) {
            int e = (wb * 128 + t) * 4;
            const float* src; unsigned short* dst;
            if (e < 32768)       { src = tw + e;           dst = wcat + e; }
            else if (e < 65536)  { src = pw + (e - 32768); dst = wcat + e; }
            else if (e < 98304)  { src = gw + (e - 65536); dst = wcat + e; }
            else                 { src = Ww + (e - 98304); dst = wwB + (e - 98304); }
            float4 f = *(const float4*)src;
            ushort4 u;
            u.x = f2bf(f.x); u.y = f2bf(f.y); u.z = f2bf(f.z); u.w = f2bf(f.w);
            *(ushort4*)dst = u;
        }
        return;
    }
    const int hw0 = blockIdx.x * 64, c0 = blockIdx.y * 64, b = blockIdx.z;
    const float* xb = x + (size_t)b * CI * HWD;
    const int rr = t >> 4, cc = t & 15;
    #pragma unroll
    for (int pass = 0; pass < 4; pass++) {
        float4 f = *(const float4*)&xb[(size_t)(c0 + pass * 16 + rr) * HWD + hw0 + cc * 4];
        T[(cc * 4 + 0) * 72 + pass * 16 + rr] = f2bf(f.x);
        T[(cc * 4 + 1) * 72 + pass * 16 + rr] = f2bf(f.y);
        T[(cc * 4 + 2) * 72 + pass * 16 + rr] = f2bf(f.z);
        T[(cc * 4 + 3) * 72 + pass * 16 + rr] = f2bf(f.w);
    }
    __syncthreads();
    const int row = t >> 2, cs = (t & 3) * 16;
    unsigned short* dst = xT + (size_t)b * NN_ * CI;
    #pragma unroll
    for (int h = 0; h < 2; h++)
        *(u8s*)&dst[(size_t)(hw0 + row) * CI + c0 + cs + h * 8] =
            *(const u8s*)&T[row * 72 + cs + h * 8];
}

// ---------------- k1: tpg = Wcat @ x, 32x32x16, xT tile staged in LDS -------
__global__ __launch_bounds__(256, 4) void k1_mfma(
    const unsigned short* __restrict__ xT, const unsigned short* __restrict__ wcat,
    const float* __restrict__ tb, const float* __restrict__ pb,
    const float* __restrict__ gb,
    unsigned short* __restrict__ thetaB, unsigned short* __restrict__ phiTB,
    unsigned short* __restrict__ gB)
{
    __shared__ unsigned short LdsX[64 * 268];
    unsigned short* T = LdsX;
    const int t = threadIdx.x;
    const int lane = t & 63, w = t >> 6;
    const int l31 = lane & 31, lh = lane >> 5;
    const int qj = w >> 1, qh = w & 1;
    const int hw0 = blockIdx.x * 64, j0 = blockIdx.y * 64, b = blockIdx.z;
    const int matId = j0 >> 7, jl0 = j0 & 127;
    const float* bvec = (matId == 0) ? tb : (matId == 1) ? pb : gb;
    const unsigned short* xb = xT + (size_t)b * NN_ * CI;

    {
        const int row = t >> 2, seg = t & 3;
        #pragma unroll
        for (int c8 = 0; c8 < 8; c8++)
            *(u8s*)&LdsX[row * 268 + seg * 64 + c8 * 8] =
                *(const u8s*)&xb[(size_t)(hw0 + row) * CI + seg * 64 + c8 * 8];
    }
    __syncthreads();

    v16f s = {};
    #pragma unroll
    for (int kt = 0; kt < 16; kt++) {
        v8s a = *(const v8s*)&wcat[(size_t)(j0 + qj * 32 + l31) * CI + kt * 16 + lh * 8];
        v8s bx = *(const v8s*)&LdsX[(qh * 32 + l31) * 268 + kt * 16 + lh * 8];
        s = MFMA32(a, bx, s);
    }

    if (matId != 1) {
        unsigned short* dst = ((matId == 0) ? thetaB : gB) + (size_t)b * CB * HWD;
        #pragma unroll
        for (int reg = 0; reg < 16; reg++) {
            int row = (reg & 3) + 8 * (reg >> 2) + 4 * lh;
            int cb = jl0 + qj * 32 + row;
            dst[(size_t)cb * HWD + hw0 + qh * 32 + l31] = f2bf(s[reg] + bvec[cb]);
        }
    } else {
        __syncthreads();
        #pragma unroll
        for (int reg = 0; reg < 16; reg++) {
            int row = (reg & 3) + 8 * (reg >> 2) + 4 * lh;
            T[(qh * 32 + l31) * 76 + qj * 32 + row] =
                f2bf(s[reg] + bvec[jl0 + qj * 32 + row]);
        }
        __syncthreads();
        unsigned short* dst = phiTB + (size_t)b * NN_ * CB;
        const int row = t >> 2, cs = (t & 3) * 16;
        #pragma unroll
        for (int h = 0; h < 2; h++)
            *(u8s*)&dst[(size_t)(hw0 + row) * CB + jl0 + cs + h * 8] =
                *(const u8s*)&T[row * 76 + cs + h * 8];
    }
}

// ---------------- k2: D[m] = sum_n exp(S[n][m]), m-tile 128 -----------------
// grid (32 m-blocks, 4 q, B). Persistent phi frags for 128 m (8 tiles).
__global__ __launch_bounds__(256, 2) void k2_colsum(
    const unsigned short* __restrict__ thetaB,
    const unsigned short* __restrict__ phiTB,
    float* __restrict__ Dout)
{
    __shared__ float part[4][128];
    const int t = threadIdx.x;
    const int lane = t & 63, w = t >> 6;
    const int ln = lane & 15, quad = lane >> 4;
    const int m0 = blockIdx.x * 128, q = blockIdx.y, b = blockIdx.z;
    const unsigned short* th = thetaB + (size_t)b * NN_ * CB;
    const unsigned short* ph = phiTB + (size_t)b * NN_ * CB;

    v8s bf[8][4];
    #pragma unroll
    for (int mt = 0; mt < 8; mt++)
        #pragma unroll
        for (int kt = 0; kt < 4; kt++)
            bf[mt][kt] = *(const v8s*)&ph[(size_t)(m0 + mt * 16 + ln) * CB + kt * 32 + quad * 8];

    float dsum[8] = {};
    const int nBeg = q * 1024 + w * 16, nEnd = q * 1024 + 1024;
    v8s af[4], afn[4];
    #pragma unroll
    for (int kt = 0; kt < 4; kt++)
        af[kt] = *(const v8s*)&th[(size_t)(nBeg + ln) * CB + kt * 32 + quad * 8];
    for (int n0 = nBeg; n0 < nEnd; n0 += 64) {
        int nn = (n0 + 64 < nEnd) ? n0 + 64 : nBeg;
        #pragma unroll
        for (int kt = 0; kt < 4; kt++)
            afn[kt] = *(const v8s*)&th[(size_t)(nn + ln) * CB + kt * 32 + quad * 8];
        #pragma unroll
        for (int mt = 0; mt < 8; mt++) {
            v4f s = {};
            #pragma unroll
            for (int kt = 0; kt < 4; kt++)
                s = MFMA16(af[kt], bf[mt][kt], s);
            #pragma unroll
            for (int r = 0; r < 4; r++)
                dsum[mt] += __expf(s[r]);
        }
        #pragma unroll
        for (int kt = 0; kt < 4; kt++) af[kt] = afn[kt];
    }
    #pragma unroll
    for (int mt = 0; mt < 8; mt++) {
        float v = dsum[mt];
        v += __shfl_xor(v, 16);
        v += __shfl_xor(v, 32);
        dsum[mt] = v;
    }
    if (quad == 0) {
        #pragma unroll
        for (int mt = 0; mt < 8; mt++) part[w][mt * 16 + ln] = dsum[mt];
    }
    __syncthreads();
    if (t < 128) {
        float v = part[0][t] + part[1][t] + part[2][t] + part[3][t];
        Dout[((size_t)q * NBATCH + b) * NN_ + m0 + t] = v;
    }
}

// ---------------- k1b: gT[c][m] = F[m*128+c] / D[m], LDS transpose ----------
__global__ __launch_bounds__(256) void k1b_transpose_scale_g(
    const unsigned short* __restrict__ gB, const float* __restrict__ D,
    unsigned short* __restrict__ gTB)
{
    __shared__ unsigned short T[128 * 36];
    const int t = threadIdx.x;
    const int m0 = blockIdx.x * 32;
    const int b  = blockIdx.z;
    const unsigned short* F = gB + (size_t)b * CB * HWD;
    unsigned short* dst = gTB + (size_t)b * CB * HWD;
    const int mrow = t >> 3, cg = t & 7;
    {
        int m = m0 + mrow;
        float d = D[((size_t)0 * NBATCH + b) * NN_ + m]
                + D[((size_t)1 * NBATCH + b) * NN_ + m]
                + D[((size_t)2 * NBATCH + b) * NN_ + m]
                + D[((size_t)3 * NBATCH + b) * NN_ + m];
        float r = 1.0f / d;
        #pragma unroll
        for (int j8 = 0; j8 < 2; j8++) {
            int cbase = cg * 8 + j8 * 64;
            u8s u = *(const u8s*)&F[(size_t)m * CB + cbase];
            #pragma unroll
            for (int e = 0; e < 8; e++)
                T[(cbase + e) * 36 + mrow] = f2bf(bf2f(u[e]) * r);
        }
    }
    __syncthreads();
    const int c = t >> 1, mh = (t & 1) * 16;
    #pragma unroll
    for (int h8 = 0; h8 < 2; h8++)
        *(u8s*)&dst[(size_t)c * HWD + m0 + mh + h8 * 8] =
            *(const u8s*)&T[c * 36 + mh + h8 * 8];
}

// ---------------- k3: y[n][c] = sum_m exp(S[n][m]) * gT[c][m] ---------------
// Round 8: block = 128n x 64c, m-quarters. grid (64, 4, B) = 1024 blocks.
// blockIdx.x = nb*2 + ch: nb = n-block (128 rows), ch = c-half (64 cols).
// S: wave w -> m-half qm=w&1, n-pair qn2=w>>1 (rows qn2*64 + {0,32}).
// PV: wave w -> c-strip (w&1)*32 within the half, n-half (w>>1)*64.
__global__ __launch_bounds__(256, 3) void k3_attn(
    const unsigned short* __restrict__ thetaB,
    const unsigned short* __restrict__ phiTB,
    const unsigned short* __restrict__ gTB,
    unsigned short* __restrict__ Y)
{
    __shared__ unsigned short Pl[128 * 76];   // [n-local][m-local 64]
    const int t = threadIdx.x;
    const int lane = t & 63, w = t >> 6;
    const int l31 = lane & 31, lh = lane >> 5;
    const int qm = w & 1, qn2 = w >> 1;
    const int nb = blockIdx.x >> 1, ch = blockIdx.x & 1;
    const int n0 = nb * 128, c0 = ch * 64;
    const int q = blockIdx.y, b = blockIdx.z;
    const unsigned short* th = thetaB + (size_t)b * NN_ * CB;
    const unsigned short* ph = phiTB + (size_t)b * NN_ * CB;
    const unsigned short* gT = gTB + (size_t)b * CB * HWD;

    // persistent theta A-frags: two 32-row strips
    v8s ath[2][8];
    #pragma unroll
    for (int s2 = 0; s2 < 2; s2++)
        #pragma unroll
        for (int kt = 0; kt < 8; kt++)
            ath[s2][kt] = *(const v8s*)&th[(size_t)(n0 + qn2 * 64 + s2 * 32 + l31) * CB + kt * 16 + lh * 8];

    const int mBeg = q * 1024, mEnd = mBeg + 1024;
    v16f yacc[2] = {};
    for (int m0 = mBeg; m0 < mEnd; m0 += 64) {
        // S phase: 2 quadrants per wave, shared bphi
        v16f s0 = {}, s1 = {};
        #pragma unroll
        for (int kt = 0; kt < 8; kt++) {
            v8s bphi = *(const v8s*)&ph[(size_t)(m0 + qm * 32 + l31) * CB + kt * 16 + lh * 8];
            s0 = MFMA32(ath[0][kt], bphi, s0);
            s1 = MFMA32(ath[1][kt], bphi, s1);
        }
        __syncthreads();   // prior PV reads of Pl complete
        #pragma unroll
        for (int reg = 0; reg < 16; reg++) {
            int rbase = (reg & 3) + 8 * (reg >> 2) + 4 * lh;
            Pl[(qn2 * 64 + rbase) * 76 + qm * 32 + l31] = f2bf(__expf(s0[reg]));
            Pl[(qn2 * 64 + 32 + rbase) * 76 + qm * 32 + l31] = f2bf(__expf(s1[reg]));
        }
        __syncthreads();   // Pl visible to all waves
        // PV phase: wave's 32-c strip, its 64-n half (2 n-tiles)
        #pragma unroll
        for (int kstep = 0; kstep < 4; kstep++) {
            v8s bg = *(const v8s*)&gT[(size_t)(c0 + (w & 1) * 32 + l31) * HWD + m0 + kstep * 16 + lh * 8];
            #pragma unroll
            for (int nt = 0; nt < 2; nt++) {
                v8s ap = *(const v8s*)&Pl[((w >> 1) * 64 + nt * 32 + l31) * 76 + kstep * 16 + lh * 8];
                yacc[nt] = MFMA32(ap, bg, yacc[nt]);
            }
        }
    }
    unsigned short* yp = Y + ((size_t)q * NBATCH + b) * CB * HWD;
    #pragma unroll
    for (int nt = 0; nt < 2; nt++)
        #pragma unroll
        for (int reg = 0; reg < 16; reg++) {
            int row = (reg & 3) + 8 * (reg >> 2) + 4 * lh;
            yp[(size_t)(n0 + (w >> 1) * 64 + nt * 32 + row) * CB + c0 + (w & 1) * 32 + l31] =
                f2bf(yacc[nt][reg]);
        }
}

// ---------------- k4: out = Ww @ (sum Y partials) + Wb + x ------------------
__global__ __launch_bounds__(256, 2) void k4_mfma(
    const float* __restrict__ x, const unsigned short* __restrict__ wwB,
    const float* __restrict__ Wb, const unsigned short* __restrict__ Ybuf,
    float* __restrict__ out)
{
    __shared__ unsigned short Yt[64 * 136];
    const int t = threadIdx.x;
    const int lane = t & 63, w = t >> 6;
    const int ln = lane & 15, quad = lane >> 4;
    const int hw0 = blockIdx.x * 64, o0 = blockIdx.y * 128, b = blockIdx.z;

    const int cb = t >> 1, seg = (t & 1) * 32;
    #pragma unroll
    for (int g8 = 0; g8 < 4; g8++) {
        float sum[8] = {};
        #pragma unroll
        for (int q = 0; q < 4; q++) {
            u8s u = *(const u8s*)&Ybuf[((size_t)q * NBATCH + b) * CB * HWD +
                                       (size_t)cb * HWD + hw0 + seg + g8 * 8];
            #pragma unroll
            for (int j = 0; j < 8; j++) sum[j] += bf2f(u[j]);
        }
        #pragma unroll
        for (int j = 0; j < 8; j++)
            Yt[(seg + g8 * 8 + j) * 136 + cb] = f2bf(sum[j]);
    }
    __syncthreads();

    v8s aw[2][4];
    #pragma unroll
    for (int os = 0; os < 2; os++)
        #pragma unroll
        for (int kt = 0; kt < 4; kt++)
            aw[os][kt] = *(const v8s*)&wwB[(size_t)(o0 + w * 32 + os * 16 + ln) * CB + kt * 32 + quad * 8];

    v4f s[2][4] = {};
    #pragma unroll
    for (int kt = 0; kt < 4; kt++) {
        v8s by[4];
        #pragma unroll
        for (int mt = 0; mt < 4; mt++)
            by[mt] = *(const v8s*)&Yt[(mt * 16 + ln) * 136 + kt * 32 + quad * 8];
        #pragma unroll
        for (int os = 0; os < 2; os++)
            #pragma unroll
            for (int mt = 0; mt < 4; mt++)
                s[os][mt] = MFMA16(aw[os][kt], by[mt], s[os][mt]);
    }
    #pragma unroll
    for (int os = 0; os < 2; os++)
        #pragma unroll
        for (int mt = 0; mt < 4; mt++)
            #pragma unroll
            for (int r = 0; r < 4; r++) {
                int o = o0 + w * 32 + os * 16 + quad * 4 + r;
                size_t idx = (size_t)b * CI * HWD + (size_t)o * HWD + hw0 + mt * 16 + ln;
                out[idx] = s[os][mt][r] + Wb[o] + x[idx];
            }
}

extern "C" void kernel_launch(void* const* d_in, const int* in_sizes, int n_in,
                              void* d_out, int out_size, void* d_ws, size_t ws_size,
                              hipStream_t stream)
{
    const float* x  = (const float*)d_in[0];
    const float* tw = (const float*)d_in[1];
    const float* tb = (const float*)d_in[2];
    const float* pw = (const float*)d_in[3];
    const float* pb = (const float*)d_in[4];
    const float* gw = (const float*)d_in[5];
    const float* gb = (const float*)d_in[6];
    const float* Ww = (const float*)d_in[7];
    const float* Wb = (const float*)d_in[8];
    unsigned short* wsu = (unsigned short*)d_ws;
    float* wsf = (float*)d_ws;
    unsigned short* thetaB = wsu + U_THETA;
    unsigned short* phiTB  = wsu + U_PHIT;
    unsigned short* gB     = wsu + U_G;
    unsigned short* gTB    = wsu + U_GT;
    unsigned short* Ybuf   = wsu + U_Y;
    unsigned short* xTB    = wsu + U_XT;
    unsigned short* wcatB  = wsu + U_WCAT;
    unsigned short* wwB    = wsu + U_WW;
    float* Dbuf = wsf + F_D;
    float* out = (float*)d_out;
    dim3 blk(256, 1, 1);
    hipLaunchKernelGGL(k0_xpose, dim3(64, 5, NBATCH), blk, 0, stream,
                       x, xTB, tw, pw, gw, Ww, wcatB, wwB);
    hipLaunchKernelGGL(k1_mfma, dim3(64, 6, NBATCH), blk, 0, stream,
                       xTB, wcatB, tb, pb, gb, thetaB, phiTB, gB);
    hipLaunchKernelGGL(k2_colsum, dim3(32, 4, NBATCH), blk, 0, stream,
                       thetaB, phiTB, Dbuf);
    hipLaunchKernelGGL(k1b_transpose_scale_g, dim3(128, 1, NBATCH), blk, 0, stream,
                       gB, Dbuf, gTB);
    hipLaunchKernelGGL(k3_attn, dim3(64, 4, NBATCH), blk, 0, stream,
                       thetaB, phiTB, gTB, Ybuf);
    hipLaunchKernelGGL(k4_mfma, dim3(64, 2, NBATCH), blk, 0, stream,
                       x, wwB, Wb, Ybuf, out);
}

// Round 9
// 235.592 us; speedup vs baseline: 1.1105x; 1.1105x over previous
//
#include <hip/hip_runtime.h>
#include <math.h>

// NonLocalBlock: B=4, C=256, Cb=128, H=W=64, N=HW=4096.
// Round 9: r8 post-mortem: launch_bounds(256,3) on k3 caused VGPR spills
// (VGPR=80 < live set) -> 2x regression. Revert k3 to r6 tiling with:
//   - single barrier/iter via double-buffered Pl
//   - gT prefetch at iteration top
//   - phi direct from global (L1 dedupes; no Lphi staging/barrier)
// Keep r8's k2 (m-tile 128; others sum dropped 150->104 us).
constexpr int CI = 256;
constexpr int CB = 128;
constexpr int HWD = 4096;
constexpr int NBATCH = 4;
constexpr int NN_ = 4096;
constexpr size_t U1 = (size_t)NBATCH * NN_ * CB;            // 2,097,152
constexpr size_t U_THETA = 0;
constexpr size_t U_PHIT  = U1;
constexpr size_t U_G     = 2 * U1;
constexpr size_t U_GT    = 3 * U1;
constexpr size_t U_Y     = 4 * U1;                          // 4 m-quarter partials
constexpr size_t U_XT    = 4 * U1;                          // alias (xT dead before k3)
constexpr size_t U_WCAT  = 8 * U1;
constexpr size_t U_WW    = 8 * U1 + 98304;
constexpr size_t F_D     = (8 * U1 + 131072) / 2;

typedef short v8s __attribute__((ext_vector_type(8)));
typedef unsigned short u8s __attribute__((ext_vector_type(8)));
typedef float v4f __attribute__((ext_vector_type(4)));
typedef float v16f __attribute__((ext_vector_type(16)));
#define MFMA16(a, b, c) __builtin_amdgcn_mfma_f32_16x16x32_bf16(a, b, c, 0, 0, 0)
#define MFMA32(a, b, c) __builtin_amdgcn_mfma_f32_32x32x16_bf16(a, b, c, 0, 0, 0)

__device__ __forceinline__ unsigned short f2bf(float f) {
    union { float f; unsigned u; } v; v.f = f;
    unsigned r = v.u + 0x7fff + ((v.u >> 16) & 1);
    return (unsigned short)(r >> 16);
}
__device__ __forceinline__ float bf2f(unsigned short s) {
    union { unsigned u; float f; } v; v.u = (unsigned)s << 16;
    return v.f;
}

// ---------------- k0: xT transpose + (fused) weight bf16 convert ------------
__global__ __launch_bounds__(256) void k0_xpose(
    const float* __restrict__ x, unsigned short* __restrict__ xT,
    const float* __restrict__ tw, const float* __restrict__ pw,
    const float* __restrict__ gw, const float* __restrict__ Ww,
    unsigned short* __restrict__ wcat, unsigned short* __restrict__ wwB)
{
    __shared__ unsigned short T[64 * 72];
    const int t = threadIdx.x;
    if (blockIdx.y == 4) {
        int wb = blockIdx.x + 64 * blockIdx.z;
        if (t < 128) {
            int e = (wb * 128 + t) * 4;
            const float* src; unsigned short* dst;
            if (e < 32768)       { src = tw + e;           dst = wcat + e; }
            else if (e < 65536)  { src = pw + (e - 32768); dst = wcat + e; }
            else if (e < 98304)  { src = gw + (e - 65536); dst = wcat + e; }
            else                 { src = Ww + (e - 98304); dst = wwB + (e - 98304); }
            float4 f = *(const float4*)src;
            ushort4 u;
            u.x = f2bf(f.x); u.y = f2bf(f.y); u.z = f2bf(f.z); u.w = f2bf(f.w);
            *(ushort4*)dst = u;
        }
        return;
    }
    const int hw0 = blockIdx.x * 64, c0 = blockIdx.y * 64, b = blockIdx.z;
    const float* xb = x + (size_t)b * CI * HWD;
    const int rr = t >> 4, cc = t & 15;
    #pragma unroll
    for (int pass = 0; pass < 4; pass++) {
        float4 f = *(const float4*)&xb[(size_t)(c0 + pass * 16 + rr) * HWD + hw0 + cc * 4];
        T[(cc * 4 + 0) * 72 + pass * 16 + rr] = f2bf(f.x);
        T[(cc * 4 + 1) * 72 + pass * 16 + rr] = f2bf(f.y);
        T[(cc * 4 + 2) * 72 + pass * 16 + rr] = f2bf(f.z);
        T[(cc * 4 + 3) * 72 + pass * 16 + rr] = f2bf(f.w);
    }
    __syncthreads();
    const int row = t >> 2, cs = (t & 3) * 16;
    unsigned short* dst = xT + (size_t)b * NN_ * CI;
    #pragma unroll
    for (int h = 0; h < 2; h++)
        *(u8s*)&dst[(size_t)(hw0 + row) * CI + c0 + cs + h * 8] =
            *(const u8s*)&T[row * 72 + cs + h * 8];
}

// ---------------- k1: tpg = Wcat @ x, 32x32x16, xT tile staged in LDS -------
__global__ __launch_bounds__(256, 4) void k1_mfma(
    const unsigned short* __restrict__ xT, const unsigned short* __restrict__ wcat,
    const float* __restrict__ tb, const float* __restrict__ pb,
    const float* __restrict__ gb,
    unsigned short* __restrict__ thetaB, unsigned short* __restrict__ phiTB,
    unsigned short* __restrict__ gB)
{
    __shared__ unsigned short LdsX[64 * 268];
    unsigned short* T = LdsX;
    const int t = threadIdx.x;
    const int lane = t & 63, w = t >> 6;
    const int l31 = lane & 31, lh = lane >> 5;
    const int qj = w >> 1, qh = w & 1;
    const int hw0 = blockIdx.x * 64, j0 = blockIdx.y * 64, b = blockIdx.z;
    const int matId = j0 >> 7, jl0 = j0 & 127;
    const float* bvec = (matId == 0) ? tb : (matId == 1) ? pb : gb;
    const unsigned short* xb = xT + (size_t)b * NN_ * CI;

    {
        const int row = t >> 2, seg = t & 3;
        #pragma unroll
        for (int c8 = 0; c8 < 8; c8++)
            *(u8s*)&LdsX[row * 268 + seg * 64 + c8 * 8] =
                *(const u8s*)&xb[(size_t)(hw0 + row) * CI + seg * 64 + c8 * 8];
    }
    __syncthreads();

    v16f s = {};
    #pragma unroll
    for (int kt = 0; kt < 16; kt++) {
        v8s a = *(const v8s*)&wcat[(size_t)(j0 + qj * 32 + l31) * CI + kt * 16 + lh * 8];
        v8s bx = *(const v8s*)&LdsX[(qh * 32 + l31) * 268 + kt * 16 + lh * 8];
        s = MFMA32(a, bx, s);
    }

    if (matId != 1) {
        unsigned short* dst = ((matId == 0) ? thetaB : gB) + (size_t)b * CB * HWD;
        #pragma unroll
        for (int reg = 0; reg < 16; reg++) {
            int row = (reg & 3) + 8 * (reg >> 2) + 4 * lh;
            int cb = jl0 + qj * 32 + row;
            dst[(size_t)cb * HWD + hw0 + qh * 32 + l31] = f2bf(s[reg] + bvec[cb]);
        }
    } else {
        __syncthreads();
        #pragma unroll
        for (int reg = 0; reg < 16; reg++) {
            int row = (reg & 3) + 8 * (reg >> 2) + 4 * lh;
            T[(qh * 32 + l31) * 76 + qj * 32 + row] =
                f2bf(s[reg] + bvec[jl0 + qj * 32 + row]);
        }
        __syncthreads();
        unsigned short* dst = phiTB + (size_t)b * NN_ * CB;
        const int row = t >> 2, cs = (t & 3) * 16;
        #pragma unroll
        for (int h = 0; h < 2; h++)
            *(u8s*)&dst[(size_t)(hw0 + row) * CB + jl0 + cs + h * 8] =
                *(const u8s*)&T[row * 76 + cs + h * 8];
    }
}

// ---------------- k2: D[m] = sum_n exp(S[n][m]), m-tile 128 -----------------
__global__ __launch_bounds__(256, 2) void k2_colsum(
    const unsigned short* __restrict__ thetaB,
    const unsigned short* __restrict__ phiTB,
    float* __restrict__ Dout)
{
    __shared__ float part[4][128];
    const int t = threadIdx.x;
    const int lane = t & 63, w = t >> 6;
    const int ln = lane & 15, quad = lane >> 4;
    const int m0 = blockIdx.x * 128, q = blockIdx.y, b = blockIdx.z;
    const unsigned short* th = thetaB + (size_t)b * NN_ * CB;
    const unsigned short* ph = phiTB + (size_t)b * NN_ * CB;

    v8s bf[8][4];
    #pragma unroll
    for (int mt = 0; mt < 8; mt++)
        #pragma unroll
        for (int kt = 0; kt < 4; kt++)
            bf[mt][kt] = *(const v8s*)&ph[(size_t)(m0 + mt * 16 + ln) * CB + kt * 32 + quad * 8];

    float dsum[8] = {};
    const int nBeg = q * 1024 + w * 16, nEnd = q * 1024 + 1024;
    v8s af[4], afn[4];
    #pragma unroll
    for (int kt = 0; kt < 4; kt++)
        af[kt] = *(const v8s*)&th[(size_t)(nBeg + ln) * CB + kt * 32 + quad * 8];
    for (int n0 = nBeg; n0 < nEnd; n0 += 64) {
        int nn = (n0 + 64 < nEnd) ? n0 + 64 : nBeg;
        #pragma unroll
        for (int kt = 0; kt < 4; kt++)
            afn[kt] = *(const v8s*)&th[(size_t)(nn + ln) * CB + kt * 32 + quad * 8];
        #pragma unroll
        for (int mt = 0; mt < 8; mt++) {
            v4f s = {};
            #pragma unroll
            for (int kt = 0; kt < 4; kt++)
                s = MFMA16(af[kt], bf[mt][kt], s);
            #pragma unroll
            for (int r = 0; r < 4; r++)
                dsum[mt] += __expf(s[r]);
        }
        #pragma unroll
        for (int kt = 0; kt < 4; kt++) af[kt] = afn[kt];
    }
    #pragma unroll
    for (int mt = 0; mt < 8; mt++) {
        float v = dsum[mt];
        v += __shfl_xor(v, 16);
        v += __shfl_xor(v, 32);
        dsum[mt] = v;
    }
    if (quad == 0) {
        #pragma unroll
        for (int mt = 0; mt < 8; mt++) part[w][mt * 16 + ln] = dsum[mt];
    }
    __syncthreads();
    if (t < 128) {
        float v = part[0][t] + part[1][t] + part[2][t] + part[3][t];
        Dout[((size_t)q * NBATCH + b) * NN_ + m0 + t] = v;
    }
}

// ---------------- k1b: gT[c][m] = F[m*128+c] / D[m], LDS transpose ----------
__global__ __launch_bounds__(256) void k1b_transpose_scale_g(
    const unsigned short* __restrict__ gB, const float* __restrict__ D,
    unsigned short* __restrict__ gTB)
{
    __shared__ unsigned short T[128 * 36];
    const int t = threadIdx.x;
    const int m0 = blockIdx.x * 32;
    const int b  = blockIdx.z;
    const unsigned short* F = gB + (size_t)b * CB * HWD;
    unsigned short* dst = gTB + (size_t)b * CB * HWD;
    const int mrow = t >> 3, cg = t & 7;
    {
        int m = m0 + mrow;
        float d = D[((size_t)0 * NBATCH + b) * NN_ + m]
                + D[((size_t)1 * NBATCH + b) * NN_ + m]
                + D[((size_t)2 * NBATCH + b) * NN_ + m]
                + D[((size_t)3 * NBATCH + b) * NN_ + m];
        float r = 1.0f / d;
        #pragma unroll
        for (int j8 = 0; j8 < 2; j8++) {
            int cbase = cg * 8 + j8 * 64;
            u8s u = *(const u8s*)&F[(size_t)m * CB + cbase];
            #pragma unroll
            for (int e = 0; e < 8; e++)
                T[(cbase + e) * 36 + mrow] = f2bf(bf2f(u[e]) * r);
        }
    }
    __syncthreads();
    const int c = t >> 1, mh = (t & 1) * 16;
    #pragma unroll
    for (int h8 = 0; h8 < 2; h8++)
        *(u8s*)&dst[(size_t)c * HWD + m0 + mh + h8 * 8] =
            *(const u8s*)&T[c * 36 + mh + h8 * 8];
}

// ---------------- k3: y[n][c] = sum_m exp(S[n][m]) * gT[c][m] ---------------
// Round 9: 64n x 128c block, m-quarters, grid (64,4,B) = 1024 blocks.
// S: wave quadrant (qn=w&1, qm=w>>1), phi direct from global (L1 dedupes).
// ONE barrier/iter: Pl double-buffered (write buf, barrier, PV reads buf).
// gT frags prefetched at iteration top (latency hidden behind S phase).
__global__ __launch_bounds__(256, 4) void k3_attn(
    const unsigned short* __restrict__ thetaB,
    const unsigned short* __restrict__ phiTB,
    const unsigned short* __restrict__ gTB,
    unsigned short* __restrict__ Y)
{
    __shared__ unsigned short Pl[2][64 * 72];   // [buf][n-local][m-local]
    const int t = threadIdx.x;
    const int lane = t & 63, w = t >> 6;
    const int l31 = lane & 31, lh = lane >> 5;
    const int qn = w & 1, qm = w >> 1;
    const int n0 = blockIdx.x * 64, q = blockIdx.y, b = blockIdx.z;
    const unsigned short* th = thetaB + (size_t)b * NN_ * CB;
    const unsigned short* ph = phiTB + (size_t)b * NN_ * CB;
    const unsigned short* gT = gTB + (size_t)b * CB * HWD;

    // persistent theta A-frags: rows n0 + qn*32 + l31
    v8s ath[8];
    #pragma unroll
    for (int kt = 0; kt < 8; kt++)
        ath[kt] = *(const v8s*)&th[(size_t)(n0 + qn * 32 + l31) * CB + kt * 16 + lh * 8];

    const int mBeg = q * 1024, mEnd = mBeg + 1024;
    v16f yacc[2] = {};
    int buf = 0;
    for (int m0 = mBeg; m0 < mEnd; m0 += 64, buf ^= 1) {
        // gT prefetch for this iter (consumed after the barrier in PV)
        v8s gfrag[4];
        #pragma unroll
        for (int ks = 0; ks < 4; ks++)
            gfrag[ks] = *(const v8s*)&gT[(size_t)(w * 32 + l31) * HWD + m0 + ks * 16 + lh * 8];
        // S phase: quadrant (qn, qm), phi from global (L1-hot across waves)
        v16f s = {};
        #pragma unroll
        for (int kt = 0; kt < 8; kt++) {
            v8s bphi = *(const v8s*)&ph[(size_t)(m0 + qm * 32 + l31) * CB + kt * 16 + lh * 8];
            s = MFMA32(ath[kt], bphi, s);
        }
        // exp + write P into Pl[buf] (other buffer is being PV-read-free)
        #pragma unroll
        for (int reg = 0; reg < 16; reg++) {
            int row = qn * 32 + (reg & 3) + 8 * (reg >> 2) + 4 * lh;
            Pl[buf][row * 72 + qm * 32 + l31] = f2bf(__expf(s[reg]));
        }
        __syncthreads();   // the single barrier: P visible; prev PV done
        // PV phase: wave's 32-c strip (w*32), both n 32-halves
        #pragma unroll
        for (int ks = 0; ks < 4; ks++)
            #pragma unroll
            for (int nt = 0; nt < 2; nt++) {
                v8s ap = *(const v8s*)&Pl[buf][(nt * 32 + l31) * 72 + ks * 16 + lh * 8];
                yacc[nt] = MFMA32(ap, gfrag[ks], yacc[nt]);
            }
    }
    unsigned short* yp = Y + ((size_t)q * NBATCH + b) * CB * HWD;
    #pragma unroll
    for (int nt = 0; nt < 2; nt++)
        #pragma unroll
        for (int reg = 0; reg < 16; reg++) {
            int row = (reg & 3) + 8 * (reg >> 2) + 4 * lh;
            yp[(size_t)(n0 + nt * 32 + row) * CB + w * 32 + l31] = f2bf(yacc[nt][reg]);
        }
}

// ---------------- k4: out = Ww @ (sum Y partials) + Wb + x ------------------
__global__ __launch_bounds__(256, 2) void k4_mfma(
    const float* __restrict__ x, const unsigned short* __restrict__ wwB,
    const float* __restrict__ Wb, const unsigned short* __restrict__ Ybuf,
    float* __restrict__ out)
{
    __shared__ unsigned short Yt[64 * 136];
    const int t = threadIdx.x;
    const int lane = t & 63, w = t >> 6;
    const int ln = lane & 15, quad = lane >> 4;
    const int hw0 = blockIdx.x * 64, o0 = blockIdx.y * 128, b = blockIdx.z;

    const int cb = t >> 1, seg = (t & 1) * 32;
    #pragma unroll
    for (int g8 = 0; g8 < 4; g8++) {
        float sum[8] = {};
        #pragma unroll
        for (int q = 0; q < 4; q++) {
            u8s u = *(const u8s*)&Ybuf[((size_t)q * NBATCH + b) * CB * HWD +
                                       (size_t)cb * HWD + hw0 + seg + g8 * 8];
            #pragma unroll
            for (int j = 0; j < 8; j++) sum[j] += bf2f(u[j]);
        }
        #pragma unroll
        for (int j = 0; j < 8; j++)
            Yt[(seg + g8 * 8 + j) * 136 + cb] = f2bf(sum[j]);
    }
    __syncthreads();

    v8s aw[2][4];
    #pragma unroll
    for (int os = 0; os < 2; os++)
        #pragma unroll
        for (int kt = 0; kt < 4; kt++)
            aw[os][kt] = *(const v8s*)&wwB[(size_t)(o0 + w * 32 + os * 16 + ln) * CB + kt * 32 + quad * 8];

    v4f s[2][4] = {};
    #pragma unroll
    for (int kt = 0; kt < 4; kt++) {
        v8s by[4];
        #pragma unroll
        for (int mt = 0; mt < 4; mt++)
            by[mt] = *(const v8s*)&Yt[(mt * 16 + ln) * 136 + kt * 32 + quad * 8];
        #pragma unroll
        for (int os = 0; os < 2; os++)
            #pragma unroll
            for (int mt = 0; mt < 4; mt++)
                s[os][mt] = MFMA16(aw[os][kt], by[mt], s[os][mt]);
    }
    #pragma unroll
    for (int os = 0; os < 2; os++)
        #pragma unroll
        for (int mt = 0; mt < 4; mt++)
            #pragma unroll
            for (int r = 0; r < 4; r++) {
                int o = o0 + w * 32 + os * 16 + quad * 4 + r;
                size_t idx = (size_t)b * CI * HWD + (size_t)o * HWD + hw0 + mt * 16 + ln;
                out[idx] = s[os][mt][r] + Wb[o] + x[idx];
            }
}

extern "C" void kernel_launch(void* const* d_in, const int* in_sizes, int n_in,
                              void* d_out, int out_size, void* d_ws, size_t ws_size,
                              hipStream_t stream)
{
    const float* x  = (const float*)d_in[0];
    const float* tw = (const float*)d_in[1];
    const float* tb = (const float*)d_in[2];
    const float* pw = (const float*)d_in[3];
    const float* pb = (const float*)d_in[4];
    const float* gw = (const float*)d_in[5];
    const float* gb = (const float*)d_in[6];
    const float* Ww = (const float*)d_in[7];
    const float* Wb = (const float*)d_in[8];
    unsigned short* wsu = (unsigned short*)d_ws;
    float* wsf = (float*)d_ws;
    unsigned short* thetaB = wsu + U_THETA;
    unsigned short* phiTB  = wsu + U_PHIT;
    unsigned short* gB     = wsu + U_G;
    unsigned short* gTB    = wsu + U_GT;
    unsigned short* Ybuf   = wsu + U_Y;
    unsigned short* xTB    = wsu + U_XT;
    unsigned short* wcatB  = wsu + U_WCAT;
    unsigned short* wwB    = wsu + U_WW;
    float* Dbuf = wsf + F_D;
    float* out = (float*)d_out;
    dim3 blk(256, 1, 1);
    hipLaunchKernelGGL(k0_xpose, dim3(64, 5, NBATCH), blk, 0, stream,
                       x, xTB, tw, pw, gw, Ww, wcatB, wwB);
    hipLaunchKernelGGL(k1_mfma, dim3(64, 6, NBATCH), blk, 0, stream,
                       xTB, wcatB, tb, pb, gb, thetaB, phiTB, gB);
    hipLaunchKernelGGL(k2_colsum, dim3(32, 4, NBATCH), blk, 0, stream,
                       thetaB, phiTB, Dbuf);
    hipLaunchKernelGGL(k1b_transpose_scale_g, dim3(128, 1, NBATCH), blk, 0, stream,
                       gB, Dbuf, gTB);
    hipLaunchKernelGGL(k3_attn, dim3(64, 4, NBATCH), blk, 0, stream,
                       thetaB, phiTB, gTB, Ybuf);
    hipLaunchKernelGGL(k4_mfma, dim3(64, 2, NBATCH), blk, 0, stream,
                       x, wwB, Wb, Ybuf, out);
}

// Round 10
// 192.622 us; speedup vs baseline: 1.3583x; 1.2231x over previous
//
#include <hip/hip_runtime.h>
#include <math.h>

// NonLocalBlock: B=4, C=256, Cb=128, H=W=64, N=HW=4096.
// Round 10: consolidate. r9 post-mortem: global-phi S phase collapsed regalloc
// (VGPR=48, serialized VMEM chain). k3 reverts to the PROVEN r6 shape
// (Lphi LDS staging + 2 barriers, 60.6us) with ONE delta: gT prefetch at
// iteration top (r5-proven). Others = r8's proven set (k2 m-tile 128 etc).
constexpr int CI = 256;
constexpr int CB = 128;
constexpr int HWD = 4096;
constexpr int NBATCH = 4;
constexpr int NN_ = 4096;
constexpr size_t U1 = (size_t)NBATCH * NN_ * CB;            // 2,097,152
constexpr size_t U_THETA = 0;
constexpr size_t U_PHIT  = U1;
constexpr size_t U_G     = 2 * U1;
constexpr size_t U_GT    = 3 * U1;
constexpr size_t U_Y     = 4 * U1;                          // 4 m-quarter partials
constexpr size_t U_XT    = 4 * U1;                          // alias (xT dead before k3)
constexpr size_t U_WCAT  = 8 * U1;
constexpr size_t U_WW    = 8 * U1 + 98304;
constexpr size_t F_D     = (8 * U1 + 131072) / 2;

typedef short v8s __attribute__((ext_vector_type(8)));
typedef unsigned short u8s __attribute__((ext_vector_type(8)));
typedef float v4f __attribute__((ext_vector_type(4)));
typedef float v16f __attribute__((ext_vector_type(16)));
#define MFMA16(a, b, c) __builtin_amdgcn_mfma_f32_16x16x32_bf16(a, b, c, 0, 0, 0)
#define MFMA32(a, b, c) __builtin_amdgcn_mfma_f32_32x32x16_bf16(a, b, c, 0, 0, 0)

__device__ __forceinline__ unsigned short f2bf(float f) {
    union { float f; unsigned u; } v; v.f = f;
    unsigned r = v.u + 0x7fff + ((v.u >> 16) & 1);
    return (unsigned short)(r >> 16);
}
__device__ __forceinline__ float bf2f(unsigned short s) {
    union { unsigned u; float f; } v; v.u = (unsigned)s << 16;
    return v.f;
}

// ---------------- k0: xT transpose + (fused) weight bf16 convert ------------
__global__ __launch_bounds__(256) void k0_xpose(
    const float* __restrict__ x, unsigned short* __restrict__ xT,
    const float* __restrict__ tw, const float* __restrict__ pw,
    const float* __restrict__ gw, const float* __restrict__ Ww,
    unsigned short* __restrict__ wcat, unsigned short* __restrict__ wwB)
{
    __shared__ unsigned short T[64 * 72];
    const int t = threadIdx.x;
    if (blockIdx.y == 4) {
        int wb = blockIdx.x + 64 * blockIdx.z;
        if (t < 128) {
            int e = (wb * 128 + t) * 4;
            const float* src; unsigned short* dst;
            if (e < 32768)       { src = tw + e;           dst = wcat + e; }
            else if (e < 65536)  { src = pw + (e - 32768); dst = wcat + e; }
            else if (e < 98304)  { src = gw + (e - 65536); dst = wcat + e; }
            else                 { src = Ww + (e - 98304); dst = wwB + (e - 98304); }
            float4 f = *(const float4*)src;
            ushort4 u;
            u.x = f2bf(f.x); u.y = f2bf(f.y); u.z = f2bf(f.z); u.w = f2bf(f.w);
            *(ushort4*)dst = u;
        }
        return;
    }
    const int hw0 = blockIdx.x * 64, c0 = blockIdx.y * 64, b = blockIdx.z;
    const float* xb = x + (size_t)b * CI * HWD;
    const int rr = t >> 4, cc = t & 15;
    #pragma unroll
    for (int pass = 0; pass < 4; pass++) {
        float4 f = *(const float4*)&xb[(size_t)(c0 + pass * 16 + rr) * HWD + hw0 + cc * 4];
        T[(cc * 4 + 0) * 72 + pass * 16 + rr] = f2bf(f.x);
        T[(cc * 4 + 1) * 72 + pass * 16 + rr] = f2bf(f.y);
        T[(cc * 4 + 2) * 72 + pass * 16 + rr] = f2bf(f.z);
        T[(cc * 4 + 3) * 72 + pass * 16 + rr] = f2bf(f.w);
    }
    __syncthreads();
    const int row = t >> 2, cs = (t & 3) * 16;
    unsigned short* dst = xT + (size_t)b * NN_ * CI;
    #pragma unroll
    for (int h = 0; h < 2; h++)
        *(u8s*)&dst[(size_t)(hw0 + row) * CI + c0 + cs + h * 8] =
            *(const u8s*)&T[row * 72 + cs + h * 8];
}

// ---------------- k1: tpg = Wcat @ x, 32x32x16, xT tile staged in LDS -------
__global__ __launch_bounds__(256, 4) void k1_mfma(
    const unsigned short* __restrict__ xT, const unsigned short* __restrict__ wcat,
    const float* __restrict__ tb, const float* __restrict__ pb,
    const float* __restrict__ gb,
    unsigned short* __restrict__ thetaB, unsigned short* __restrict__ phiTB,
    unsigned short* __restrict__ gB)
{
    __shared__ unsigned short LdsX[64 * 268];
    unsigned short* T = LdsX;
    const int t = threadIdx.x;
    const int lane = t & 63, w = t >> 6;
    const int l31 = lane & 31, lh = lane >> 5;
    const int qj = w >> 1, qh = w & 1;
    const int hw0 = blockIdx.x * 64, j0 = blockIdx.y * 64, b = blockIdx.z;
    const int matId = j0 >> 7, jl0 = j0 & 127;
    const float* bvec = (matId == 0) ? tb : (matId == 1) ? pb : gb;
    const unsigned short* xb = xT + (size_t)b * NN_ * CI;

    {
        const int row = t >> 2, seg = t & 3;
        #pragma unroll
        for (int c8 = 0; c8 < 8; c8++)
            *(u8s*)&LdsX[row * 268 + seg * 64 + c8 * 8] =
                *(const u8s*)&xb[(size_t)(hw0 + row) * CI + seg * 64 + c8 * 8];
    }
    __syncthreads();

    v16f s = {};
    #pragma unroll
    for (int kt = 0; kt < 16; kt++) {
        v8s a = *(const v8s*)&wcat[(size_t)(j0 + qj * 32 + l31) * CI + kt * 16 + lh * 8];
        v8s bx = *(const v8s*)&LdsX[(qh * 32 + l31) * 268 + kt * 16 + lh * 8];
        s = MFMA32(a, bx, s);
    }

    if (matId != 1) {
        unsigned short* dst = ((matId == 0) ? thetaB : gB) + (size_t)b * CB * HWD;
        #pragma unroll
        for (int reg = 0; reg < 16; reg++) {
            int row = (reg & 3) + 8 * (reg >> 2) + 4 * lh;
            int cb = jl0 + qj * 32 + row;
            dst[(size_t)cb * HWD + hw0 + qh * 32 + l31] = f2bf(s[reg] + bvec[cb]);
        }
    } else {
        __syncthreads();
        #pragma unroll
        for (int reg = 0; reg < 16; reg++) {
            int row = (reg & 3) + 8 * (reg >> 2) + 4 * lh;
            T[(qh * 32 + l31) * 76 + qj * 32 + row] =
                f2bf(s[reg] + bvec[jl0 + qj * 32 + row]);
        }
        __syncthreads();
        unsigned short* dst = phiTB + (size_t)b * NN_ * CB;
        const int row = t >> 2, cs = (t & 3) * 16;
        #pragma unroll
        for (int h = 0; h < 2; h++)
            *(u8s*)&dst[(size_t)(hw0 + row) * CB + jl0 + cs + h * 8] =
                *(const u8s*)&T[row * 76 + cs + h * 8];
    }
}

// ---------------- k2: D[m] = sum_n exp(S[n][m]), m-tile 128 -----------------
__global__ __launch_bounds__(256, 2) void k2_colsum(
    const unsigned short* __restrict__ thetaB,
    const unsigned short* __restrict__ phiTB,
    float* __restrict__ Dout)
{
    __shared__ float part[4][128];
    const int t = threadIdx.x;
    const int lane = t & 63, w = t >> 6;
    const int ln = lane & 15, quad = lane >> 4;
    const int m0 = blockIdx.x * 128, q = blockIdx.y, b = blockIdx.z;
    const unsigned short* th = thetaB + (size_t)b * NN_ * CB;
    const unsigned short* ph = phiTB + (size_t)b * NN_ * CB;

    v8s bf[8][4];
    #pragma unroll
    for (int mt = 0; mt < 8; mt++)
        #pragma unroll
        for (int kt = 0; kt < 4; kt++)
            bf[mt][kt] = *(const v8s*)&ph[(size_t)(m0 + mt * 16 + ln) * CB + kt * 32 + quad * 8];

    float dsum[8] = {};
    const int nBeg = q * 1024 + w * 16, nEnd = q * 1024 + 1024;
    v8s af[4], afn[4];
    #pragma unroll
    for (int kt = 0; kt < 4; kt++)
        af[kt] = *(const v8s*)&th[(size_t)(nBeg + ln) * CB + kt * 32 + quad * 8];
    for (int n0 = nBeg; n0 < nEnd; n0 += 64) {
        int nn = (n0 + 64 < nEnd) ? n0 + 64 : nBeg;
        #pragma unroll
        for (int kt = 0; kt < 4; kt++)
            afn[kt] = *(const v8s*)&th[(size_t)(nn + ln) * CB + kt * 32 + quad * 8];
        #pragma unroll
        for (int mt = 0; mt < 8; mt++) {
            v4f s = {};
            #pragma unroll
            for (int kt = 0; kt < 4; kt++)
                s = MFMA16(af[kt], bf[mt][kt], s);
            #pragma unroll
            for (int r = 0; r < 4; r++)
                dsum[mt] += __expf(s[r]);
        }
        #pragma unroll
        for (int kt = 0; kt < 4; kt++) af[kt] = afn[kt];
    }
    #pragma unroll
    for (int mt = 0; mt < 8; mt++) {
        float v = dsum[mt];
        v += __shfl_xor(v, 16);
        v += __shfl_xor(v, 32);
        dsum[mt] = v;
    }
    if (quad == 0) {
        #pragma unroll
        for (int mt = 0; mt < 8; mt++) part[w][mt * 16 + ln] = dsum[mt];
    }
    __syncthreads();
    if (t < 128) {
        float v = part[0][t] + part[1][t] + part[2][t] + part[3][t];
        Dout[((size_t)q * NBATCH + b) * NN_ + m0 + t] = v;
    }
}

// ---------------- k1b: gT[c][m] = F[m*128+c] / D[m], LDS transpose ----------
__global__ __launch_bounds__(256) void k1b_transpose_scale_g(
    const unsigned short* __restrict__ gB, const float* __restrict__ D,
    unsigned short* __restrict__ gTB)
{
    __shared__ unsigned short T[128 * 36];
    const int t = threadIdx.x;
    const int m0 = blockIdx.x * 32;
    const int b  = blockIdx.z;
    const unsigned short* F = gB + (size_t)b * CB * HWD;
    unsigned short* dst = gTB + (size_t)b * CB * HWD;
    const int mrow = t >> 3, cg = t & 7;
    {
        int m = m0 + mrow;
        float d = D[((size_t)0 * NBATCH + b) * NN_ + m]
                + D[((size_t)1 * NBATCH + b) * NN_ + m]
                + D[((size_t)2 * NBATCH + b) * NN_ + m]
                + D[((size_t)3 * NBATCH + b) * NN_ + m];
        float r = 1.0f / d;
        #pragma unroll
        for (int j8 = 0; j8 < 2; j8++) {
            int cbase = cg * 8 + j8 * 64;
            u8s u = *(const u8s*)&F[(size_t)m * CB + cbase];
            #pragma unroll
            for (int e = 0; e < 8; e++)
                T[(cbase + e) * 36 + mrow] = f2bf(bf2f(u[e]) * r);
        }
    }
    __syncthreads();
    const int c = t >> 1, mh = (t & 1) * 16;
    #pragma unroll
    for (int h8 = 0; h8 < 2; h8++)
        *(u8s*)&dst[(size_t)c * HWD + m0 + mh + h8 * 8] =
            *(const u8s*)&T[c * 36 + mh + h8 * 8];
}

// ---------------- k3: y[n][c] = sum_m exp(S[n][m]) * gT[c][m], 32x32x16 -----
// r6-proven shape: 64n x 128c block, Lphi LDS staging (reg->LDS pipeline),
// 2 barriers/iter, quadrant S. ONE delta vs r6: gT prefetch at iter top.
__global__ __launch_bounds__(256, 4) void k3_attn(
    const unsigned short* __restrict__ thetaB,
    const unsigned short* __restrict__ phiTB,
    const unsigned short* __restrict__ gTB,
    unsigned short* __restrict__ Y)
{
    __shared__ unsigned short Lphi[64 * 140];   // [m-local][k], 280B stride
    __shared__ unsigned short Pl[64 * 76];      // [n-local][m-local], 152B stride
    const int t = threadIdx.x;
    const int lane = t & 63, w = t >> 6;
    const int l31 = lane & 31, lh = lane >> 5;
    const int qn = w & 1, qm = w >> 1;
    const int rowS = t >> 4, colS = t & 15;
    const int n0 = blockIdx.x * 64, q = blockIdx.y, b = blockIdx.z;
    const unsigned short* th = thetaB + (size_t)b * NN_ * CB;
    const unsigned short* ph = phiTB + (size_t)b * NN_ * CB;
    const unsigned short* gT = gTB + (size_t)b * CB * HWD;

    // persistent theta A-frags: rows n0+qn*32+l31, k = 128 in 8 steps of 16
    v8s ath[8];
    #pragma unroll
    for (int kt = 0; kt < 8; kt++)
        ath[kt] = *(const v8s*)&th[(size_t)(n0 + qn * 32 + l31) * CB + kt * 16 + lh * 8];

    const int mBeg = q * 1024, mEnd = mBeg + 1024;
    #pragma unroll
    for (int pass = 0; pass < 4; pass++)
        *(v8s*)&Lphi[(pass * 16 + rowS) * 140 + colS * 8] =
            *(const v8s*)&ph[(size_t)(mBeg + pass * 16 + rowS) * CB + colS * 8];
    __syncthreads();

    v16f yacc[2] = {};   // nt = 0,1 (n halves); wave's c-strip = w*32
    for (int m0 = mBeg; m0 < mEnd; m0 += 64) {
        int mN = (m0 + 64 < mEnd) ? m0 + 64 : mBeg;
        v8s preg[4];
        #pragma unroll
        for (int pass = 0; pass < 4; pass++)
            preg[pass] = *(const v8s*)&ph[(size_t)(mN + pass * 16 + rowS) * CB + colS * 8];
        // gT prefetch for this iter (consumed in PV after the 2nd barrier)
        v8s gfrag[4];
        #pragma unroll
        for (int ks = 0; ks < 4; ks++)
            gfrag[ks] = *(const v8s*)&gT[(size_t)(w * 32 + l31) * HWD + m0 + ks * 16 + lh * 8];
        // S phase: one 32x32 quadrant per wave, phi from LDS
        v16f s = {};
        #pragma unroll
        for (int kt = 0; kt < 8; kt++) {
            v8s bphi = *(const v8s*)&Lphi[(qm * 32 + l31) * 140 + kt * 16 + lh * 8];
            s = MFMA32(ath[kt], bphi, s);
        }
        __syncthreads();   // prior PV reads of Pl done; S reads of Lphi done
        #pragma unroll
        for (int reg = 0; reg < 16; reg++) {
            int row = qn * 32 + (reg & 3) + 8 * (reg >> 2) + 4 * lh;   // n-local
            Pl[row * 76 + qm * 32 + l31] = f2bf(__expf(s[reg]));
        }
        #pragma unroll
        for (int pass = 0; pass < 4; pass++)
            *(v8s*)&Lphi[(pass * 16 + rowS) * 140 + colS * 8] = preg[pass];
        __syncthreads();
        // PV phase: wave's 32-c strip (w*32), both n 32-halves
        #pragma unroll
        for (int ks = 0; ks < 4; ks++)
            #pragma unroll
            for (int nt = 0; nt < 2; nt++) {
                v8s ap = *(const v8s*)&Pl[(nt * 32 + l31) * 76 + ks * 16 + lh * 8];
                yacc[nt] = MFMA32(ap, gfrag[ks], yacc[nt]);
            }
    }
    unsigned short* yp = Y + ((size_t)q * NBATCH + b) * CB * HWD;
    #pragma unroll
    for (int nt = 0; nt < 2; nt++)
        #pragma unroll
        for (int reg = 0; reg < 16; reg++) {
            int row = (reg & 3) + 8 * (reg >> 2) + 4 * lh;
            yp[(size_t)(n0 + nt * 32 + row) * CB + w * 32 + l31] = f2bf(yacc[nt][reg]);
        }
}

// ---------------- k4: out = Ww @ (sum Y partials) + Wb + x ------------------
__global__ __launch_bounds__(256, 2) void k4_mfma(
    const float* __restrict__ x, const unsigned short* __restrict__ wwB,
    const float* __restrict__ Wb, const unsigned short* __restrict__ Ybuf,
    float* __restrict__ out)
{
    __shared__ unsigned short Yt[64 * 136];
    const int t = threadIdx.x;
    const int lane = t & 63, w = t >> 6;
    const int ln = lane & 15, quad = lane >> 4;
    const int hw0 = blockIdx.x * 64, o0 = blockIdx.y * 128, b = blockIdx.z;

    const int cb = t >> 1, seg = (t & 1) * 32;
    #pragma unroll
    for (int g8 = 0; g8 < 4; g8++) {
        float sum[8] = {};
        #pragma unroll
        for (int q = 0; q < 4; q++) {
            u8s u = *(const u8s*)&Ybuf[((size_t)q * NBATCH + b) * CB * HWD +
                                       (size_t)cb * HWD + hw0 + seg + g8 * 8];
            #pragma unroll
            for (int j = 0; j < 8; j++) sum[j] += bf2f(u[j]);
        }
        #pragma unroll
        for (int j = 0; j < 8; j++)
            Yt[(seg + g8 * 8 + j) * 136 + cb] = f2bf(sum[j]);
    }
    __syncthreads();

    v8s aw[2][4];
    #pragma unroll
    for (int os = 0; os < 2; os++)
        #pragma unroll
        for (int kt = 0; kt < 4; kt++)
            aw[os][kt] = *(const v8s*)&wwB[(size_t)(o0 + w * 32 + os * 16 + ln) * CB + kt * 32 + quad * 8];

    v4f s[2][4] = {};
    #pragma unroll
    for (int kt = 0; kt < 4; kt++) {
        v8s by[4];
        #pragma unroll
        for (int mt = 0; mt < 4; mt++)
            by[mt] = *(const v8s*)&Yt[(mt * 16 + ln) * 136 + kt * 32 + quad * 8];
        #pragma unroll
        for (int os = 0; os < 2; os++)
            #pragma unroll
            for (int mt = 0; mt < 4; mt++)
                s[os][mt] = MFMA16(aw[os][kt], by[mt], s[os][mt]);
    }
    #pragma unroll
    for (int os = 0; os < 2; os++)
        #pragma unroll
        for (int mt = 0; mt < 4; mt++)
            #pragma unroll
            for (int r = 0; r < 4; r++) {
                int o = o0 + w * 32 + os * 16 + quad * 4 + r;
                size_t idx = (size_t)b * CI * HWD + (size_t)o * HWD + hw0 + mt * 16 + ln;
                out[idx] = s[os][mt][r] + Wb[o] + x[idx];
            }
}

extern "C" void kernel_launch(void* const* d_in, const int* in_sizes, int n_in,
                              void* d_out, int out_size, void* d_ws, size_t ws_size,
                              hipStream_t stream)
{
    const float* x  = (const float*)d_in[0];
    const float* tw = (const float*)d_in[1];
    const float* tb = (const float*)d_in[2];
    const float* pw = (const float*)d_in[3];
    const float* pb = (const float*)d_in[4];
    const float* gw = (const float*)d_in[5];
    const float* gb = (const float*)d_in[6];
    const float* Ww = (const float*)d_in[7];
    const float* Wb = (const float*)d_in[8];
    unsigned short* wsu = (unsigned short*)d_ws;
    float* wsf = (float*)d_ws;
    unsigned short* thetaB = wsu + U_THETA;
    unsigned short* phiTB  = wsu + U_PHIT;
    unsigned short* gB     = wsu + U_G;
    unsigned short* gTB    = wsu + U_GT;
    unsigned short* Ybuf   = wsu + U_Y;
    unsigned short* xTB    = wsu + U_XT;
    unsigned short* wcatB  = wsu + U_WCAT;
    unsigned short* wwB    = wsu + U_WW;
    float* Dbuf = wsf + F_D;
    float* out = (float*)d_out;
    dim3 blk(256, 1, 1);
    hipLaunchKernelGGL(k0_xpose, dim3(64, 5, NBATCH), blk, 0, stream,
                       x, xTB, tw, pw, gw, Ww, wcatB, wwB);
    hipLaunchKernelGGL(k1_mfma, dim3(64, 6, NBATCH), blk, 0, stream,
                       xTB, wcatB, tb, pb, gb, thetaB, phiTB, gB);
    hipLaunchKernelGGL(k2_colsum, dim3(32, 4, NBATCH), blk, 0, stream,
                       thetaB, phiTB, Dbuf);
    hipLaunchKernelGGL(k1b_transpose_scale_g, dim3(128, 1, NBATCH), blk, 0, stream,
                       gB, Dbuf, gTB);
    hipLaunchKernelGGL(k3_attn, dim3(64, 4, NBATCH), blk, 0, stream,
                       thetaB, phiTB, gTB, Ybuf);
    hipLaunchKernelGGL(k4_mfma, dim3(64, 2, NBATCH), blk, 0, stream,
                       x, wwB, Wb, Ybuf, out);
}